// Round 14
// baseline (564.691 us; speedup 1.0000x reference)
//
#include <hip/hip_runtime.h>
#include <cstdint>
#include <cstddef>

#define BSZ 2
#define NV 16
#define SEQ 1024
#define DIM 768
#define VOC 50257
#define VOCP 50304   // padded to multiple of 128

typedef unsigned int u32;
typedef unsigned short u16;
typedef _Float16 half8 __attribute__((ext_vector_type(8)));
typedef float f32x4 __attribute__((ext_vector_type(4)));

__device__ __forceinline__ u16 f2h(float f) {
  return __builtin_bit_cast(unsigned short, (_Float16)f);
}
__device__ __forceinline__ u32 pk2h(float a, float b) {
  return (u32)f2h(a) | ((u32)f2h(b) << 16);
}

// async global->LDS, 16B per lane; LDS dest = wave-uniform base + lane*16
__device__ __forceinline__ void gload16(const u16* g, u16* l) {
  __builtin_amdgcn_global_load_lds(
      (const __attribute__((address_space(1))) void*)g,
      (__attribute__((address_space(3))) void*)l, 16, 0, 0);
}

// ---------------------------------------------------------------------------
// K1: content f32 -> f16 (normal + transposed). 64x64 tiles, float4 loads.
// grid (12, 16, 32), block 256
__global__ void k_prep_content(const float* __restrict__ content,
                               u16* __restrict__ cbf, u16* __restrict__ cT) {
  __shared__ u16 tile[64][70];
  const int bk = blockIdx.z;
  const int d0 = blockIdx.x * 64, j0 = blockIdx.y * 64;
  const float* src = content + (size_t)bk * SEQ * DIM;
  u16* dst = cbf + (size_t)bk * SEQ * DIM;
  u16* dstT = cT + (size_t)bk * DIM * SEQ;
  const int c4 = (threadIdx.x & 15) * 4;  // d-local (x4)
  const int r0 = threadIdx.x >> 4;        // 0..15
#pragma unroll
  for (int it = 0; it < 4; ++it) {
    const int r = it * 16 + r0;           // j-local
    const float4 f = *(const float4*)(src + (size_t)(j0 + r) * DIM + d0 + c4);
    const u32 lo = pk2h(f.x, f.y), hi = pk2h(f.z, f.w);
    *(uint2*)(dst + (size_t)(j0 + r) * DIM + d0 + c4) = make_uint2(lo, hi);
    *(u32*)&tile[r][c4] = lo;
    *(u32*)&tile[r][c4 + 2] = hi;
  }
  __syncthreads();
#pragma unroll
  for (int it = 0; it < 4; ++it) {
    const int dd = it * 16 + r0;          // d-local
    const int j4 = c4;                    // j-local (x4)
    const u32 lo = (u32)tile[j4][dd] | ((u32)tile[j4 + 1][dd] << 16);
    const u32 hi = (u32)tile[j4 + 2][dd] | ((u32)tile[j4 + 3][dd] << 16);
    *(uint2*)(dstT + (size_t)(d0 + dd) * SEQ + j0 + j4) = make_uint2(lo, hi);
  }
}

// K2: lm_head_weight f32 -> f16, flat grid-stride (row-major Wb). grid 2048.
__global__ void k_prep_w(const float* __restrict__ W, u16* __restrict__ Wb) {
  const size_t nW = (size_t)VOC * DIM / 4;    // uint2 units covering W
  const size_t total = (size_t)VOCP * DIM / 4;
  for (size_t u = (size_t)blockIdx.x * 256 + threadIdx.x; u < total;
       u += (size_t)gridDim.x * 256) {
    u32 lo = 0u, hi = 0u;
    if (u < nW) {
      const float4 f = *(const float4*)(W + u * 4);
      lo = pk2h(f.x, f.y); hi = pk2h(f.z, f.w);
    }
    *(uint2*)(Wb + u * 4) = make_uint2(lo, hi);
  }
}

// K3: gather Wg[b][j][:] = Wb[ids[b][j]][:]  grid (SEQ, BSZ), block 192
__global__ void k_gather(const int* __restrict__ ids, const u16* __restrict__ Wb,
                         u16* __restrict__ Wg) {
  const int b = blockIdx.y, j = blockIdx.x;
  const int row = ids[b * SEQ + j];
  const int c = threadIdx.x * 4;
  *(uint2*)(Wg + ((size_t)b * SEQ + j) * DIM + c) =
      *(const uint2*)(Wb + (size_t)row * DIM + c);
}

__global__ void k_zero(float* __restrict__ p, int n) {
  const int i = blockIdx.x * 256 + threadIdx.x;
  if (i < n) p[i] = 0.f;
}

// ---------------------------------------------------------------------------
// Dual-A ring core (round-6, verified) — used by k_sims.
template <int LDA, int LDB>
__device__ __forceinline__ void gemm_ring2(const u16* __restrict__ A0,
                                           const u16* __restrict__ A1,
                                           const u16* __restrict__ B, int ksteps,
                                           u16* As0, u16* As1, u16* Bs,
                                           f32x4 (&acc0)[4][4],
                                           f32x4 (&acc1)[4][4], int t) {
  const int lane = t & 63, w = t >> 6, wr = w >> 1, wc = w & 1;
  const int rl = lane & 15;
  const int gsw = (((lane >> 4) ^ ((rl >> 1) & 3)) * 8);
  const int srow = 16 * w + (lane >> 2);
  const int sg = (((lane & 3) ^ ((lane >> 3) & 3)) * 8);
  const size_t gaBase = (size_t)srow * LDA + sg;
  const size_t gbBase = (size_t)srow * LDB + sg;
  const int wof = w * 512;

#define STG3_(ss, kt)                                                   \
  {                                                                     \
    const u16* ga0_ = A0 + gaBase + (size_t)(kt) * 32;                  \
    const u16* ga1_ = A1 + gaBase + (size_t)(kt) * 32;                  \
    const u16* gb_ = B + gbBase + (size_t)(kt) * 32;                    \
    gload16(ga0_, As0 + (ss) * 4096 + wof);                             \
    gload16(ga0_ + (size_t)64 * LDA, As0 + (ss) * 4096 + wof + 2048);   \
    gload16(ga1_, As1 + (ss) * 4096 + wof);                            \
    gload16(ga1_ + (size_t)64 * LDA, As1 + (ss) * 4096 + wof + 2048);   \
    gload16(gb_, Bs + (ss) * 4096 + wof);                              \
    gload16(gb_ + (size_t)64 * LDB, Bs + (ss) * 4096 + wof + 2048);     \
  }

#define FRAGS3_(ss)                                                     \
  half8 af0[4], af1[4], bf[4];                                          \
  _Pragma("unroll") for (int n = 0; n < 4; ++n)                         \
      bf[n] = *(const half8*)(Bs + (ss) * 4096 +                        \
                              (wc * 64 + n * 16 + rl) * 32 + gsw);      \
  _Pragma("unroll") for (int m = 0; m < 4; ++m)                         \
      af0[m] = *(const half8*)(As0 + (ss) * 4096 +                      \
                               (wr * 64 + m * 16 + rl) * 32 + gsw);     \
  _Pragma("unroll") for (int m = 0; m < 4; ++m)                         \
      af1[m] = *(const half8*)(As1 + (ss) * 4096 +                      \
                               (wr * 64 + m * 16 + rl) * 32 + gsw);

#define MFMA32_                                                         \
  __builtin_amdgcn_s_setprio(1);                                        \
  _Pragma("unroll") for (int m = 0; m < 4; ++m)                         \
      _Pragma("unroll") for (int n = 0; n < 4; ++n)                     \
          acc0[m][n] = __builtin_amdgcn_mfma_f32_16x16x32_f16(          \
              af0[m], bf[n], acc0[m][n], 0, 0, 0);                      \
  _Pragma("unroll") for (int m = 0; m < 4; ++m)                         \
      _Pragma("unroll") for (int n = 0; n < 4; ++n)                     \
          acc1[m][n] = __builtin_amdgcn_mfma_f32_16x16x32_f16(          \
              af1[m], bf[n], acc1[m][n], 0, 0, 0);                      \
  __builtin_amdgcn_s_setprio(0);

#define STEPF_(ss, kt)                                                  \
  asm volatile("s_waitcnt vmcnt(6)" ::: "memory");                      \
  __builtin_amdgcn_s_barrier();                                         \
  __builtin_amdgcn_sched_barrier(0);                                    \
  STG3_(((ss) + 2) % 3, (kt) + 2);                                      \
  { FRAGS3_(ss) MFMA32_ }

#define STEPL6_(ss)                                                     \
  asm volatile("s_waitcnt vmcnt(6)" ::: "memory");                      \
  __builtin_amdgcn_s_barrier();                                         \
  __builtin_amdgcn_sched_barrier(0);                                    \
  { FRAGS3_(ss) MFMA32_ }

#define STEPL0_(ss)                                                     \
  asm volatile("s_waitcnt vmcnt(0)" ::: "memory");                      \
  __builtin_amdgcn_s_barrier();                                         \
  __builtin_amdgcn_sched_barrier(0);                                    \
  { FRAGS3_(ss) MFMA32_ }

  STG3_(0, 0);
  STG3_(1, 1);
  const int nTrip = ksteps / 3;
  for (int u = 0; u < nTrip - 1; ++u) {
    const int kt = 3 * u;
    STEPF_(0, kt);
    STEPF_(1, kt + 1);
    STEPF_(2, kt + 2);
  }
  STEPF_(0, ksteps - 3);
  STEPL6_(1);
  STEPL0_(2);
#undef STG3_
#undef FRAGS3_
#undef MFMA32_
#undef STEPF_
#undef STEPL6_
#undef STEPL0_
}

// K4: sims[bk][i] += sum_j relu(content[bk] @ Wg[b]^T). grid (8,4,32)
__global__ __launch_bounds__(256, 2) void k_sims(const u16* __restrict__ cbf,
                                                 const u16* __restrict__ Wg,
                                                 float* __restrict__ sims) {
  __shared__ __align__(16) u16 As0[3 * 4096];
  __shared__ __align__(16) u16 As1[3 * 4096];
  __shared__ __align__(16) u16 Bs[3 * 4096];
  const int bk = blockIdx.z, b = bk >> 4;
  const int t = threadIdx.x;
  const int i0 = blockIdx.y * 256;
  const u16* A0 = cbf + (size_t)bk * SEQ * DIM + (size_t)i0 * DIM;
  const u16* A1 = A0 + (size_t)128 * DIM;
  const u16* B = Wg + (size_t)b * SEQ * DIM + (size_t)(blockIdx.x * 128) * DIM;
  f32x4 acc0[4][4] = {}, acc1[4][4] = {};
  gemm_ring2<DIM, DIM>(A0, A1, B, DIM / 32, As0, As1, Bs, acc0, acc1, t);
  const int lane = t & 63, w = t >> 6, wr = w >> 1;
  const int rg = lane >> 4, cl = lane & 15;
#pragma unroll
  for (int m = 0; m < 4; ++m) {
#pragma unroll
    for (int r = 0; r < 4; ++r) {
      float s0 = 0.f, s1 = 0.f;
#pragma unroll
      for (int n = 0; n < 4; ++n) {
        s0 += fmaxf(acc0[m][n][r], 0.f);
        s1 += fmaxf(acc1[m][n][r], 0.f);
      }
      s0 += __shfl_xor(s0, 1); s1 += __shfl_xor(s1, 1);
      s0 += __shfl_xor(s0, 2); s1 += __shfl_xor(s1, 2);
      s0 += __shfl_xor(s0, 4); s1 += __shfl_xor(s1, 4);
      s0 += __shfl_xor(s0, 8); s1 += __shfl_xor(s1, 8);
      if (cl == 0) {
        const int i = i0 + wr * 64 + m * 16 + rg * 4 + r;
        atomicAdd(&sims[(size_t)bk * SEQ + i], s0);
        atomicAdd(&sims[(size_t)bk * SEQ + i + 128], s1);
      }
    }
  }
}

// K5: wtsT[bk][j] = cw*score + (1-score). grid (4,32), block 256
__global__ void k_weights(const float* __restrict__ sims, const int* __restrict__ ids,
                          const float* __restrict__ cw, float* __restrict__ wtsT) {
  const int j = blockIdx.x * 256 + threadIdx.x;
  const int bk = blockIdx.y;
  const int b = bk >> 4, k = bk & 15;
  const float sm = sims[(size_t)bk * SEQ + j];
  float score = 1.f / (1.f + __expf(0.1f * sm - 6.f));  // sigmoid(-0.1*s + 6)
  score *= 1.f + (float)j * 0.01f;
  const int id = ids[b * SEQ + j];
  const float c = cw[(size_t)id * NV + k];
  wtsT[(size_t)bk * SEQ + j] = c * score + (1.f - score);
}

// ---------------------------------------------------------------------------
// K7 (FUSED ctx-scale + hidden partials) — round-13 verified.
__global__ __launch_bounds__(256, 3) void k_hidden(const float* __restrict__ ctx,
                                                   const float* __restrict__ wtsT,
                                                   const u16* __restrict__ cT,
                                                   float* __restrict__ part) {
  __shared__ __align__(16) u16 As[2 * 4096];
  __shared__ __align__(16) u16 Bs[2 * 4096];
  const int L = blockIdx.x;            // 0..767
  const int g8 = L & 7, q = L >> 3;    // q 0..95
  const int p = g8 * 16 + q / 6;       // (y,z) pair 0..127
  const int dt = q % 6;
  const int y = p & 7, z = p >> 3;
  const int b = z >> 3, grp = z & 7;
  const int i0 = y * 128, d0 = dt * 128;
  const int t = threadIdx.x;
  const int lane = t & 63, w = t >> 6, wr = w >> 1, wc = w & 1;
  const int rl = lane & 15;
  const int gsw = (((lane >> 4) ^ ((rl >> 1) & 3)) * 8);  // frag read granule
  const int srow = 16 * w + (lane >> 2);                  // staging row 0..63
  const int sg = (((lane & 3) ^ ((lane >> 3) & 3)) * 8);  // staged src granule

  f32x4 acc[4][4] = {};
  float4 ra0, ra1, ra2, ra3, rw0, rw1;
  uint4 rb0, rb1;

#define LDREGS(u_)                                                      \
  {                                                                     \
    const int s_ = (u_) >> 5, kt_ = (u_) & 31;                          \
    const size_t bkq_ = (size_t)b * NV + grp * 2 + s_;                  \
    const int jsw_ = kt_ * 32 + sg;                                     \
    const float* ap_ = ctx + (bkq_ * SEQ + i0 + srow) * SEQ + jsw_;     \
    ra0 = *(const float4*)(ap_);                                        \
    ra1 = *(const float4*)(ap_ + 4);                                    \
    ra2 = *(const float4*)(ap_ + (size_t)64 * SEQ);                     \
    ra3 = *(const float4*)(ap_ + (size_t)64 * SEQ + 4);                 \
    const float* wp_ = wtsT + bkq_ * SEQ + jsw_;                        \
    rw0 = *(const float4*)(wp_);                                        \
    rw1 = *(const float4*)(wp_ + 4);                                    \
    const u16* bp_ = cT + (bkq_ * DIM + d0 + srow) * SEQ + jsw_;        \
    rb0 = *(const uint4*)(bp_);                                         \
    rb1 = *(const uint4*)(bp_ + (size_t)64 * SEQ);                      \
  }

#define WRITE(cc)                                                       \
  {                                                                     \
    u16* da_ = As + (cc) * 4096 + w * 512 + lane * 8;                   \
    *(uint4*)(da_) =                                                    \
        make_uint4(pk2h(ra0.x * rw0.x, ra0.y * rw0.y),                  \
                   pk2h(ra0.z * rw0.z, ra0.w * rw0.w),                  \
                   pk2h(ra1.x * rw1.x, ra1.y * rw1.y),                  \
                   pk2h(ra1.z * rw1.z, ra1.w * rw1.w));                 \
    *(uint4*)(da_ + 2048) =                                             \
        make_uint4(pk2h(ra2.x * rw0.x, ra2.y * rw0.y),                  \
                   pk2h(ra2.z * rw0.z, ra2.w * rw0.w),                  \
                   pk2h(ra3.x * rw1.x, ra3.y * rw1.y),                  \
                   pk2h(ra3.z * rw1.z, ra3.w * rw1.w));                 \
    u16* db_ = Bs + (cc) * 4096 + w * 512 + lane * 8;                   \
    *(uint4*)(db_) = rb0;                                               \
    *(uint4*)(db_ + 2048) = rb1;                                        \
  }

  LDREGS(0);
  int cur = 0;
#pragma unroll 1
  for (int u = 0; u < 64; ++u) {
    __syncthreads();              // buffer cur free (its frags consumed)
    WRITE(cur);
    if (u < 63) LDREGS(u + 1);    // issue next-slice loads under compute
    __syncthreads();              // writes visible to all waves
    half8 af[4], bf[4];
#pragma unroll
    for (int m = 0; m < 4; ++m)
      af[m] = *(const half8*)(As + cur * 4096 + (wr * 64 + m * 16 + rl) * 32 + gsw);
#pragma unroll
    for (int n = 0; n < 4; ++n)
      bf[n] = *(const half8*)(Bs + cur * 4096 + (wc * 64 + n * 16 + rl) * 32 + gsw);
    __builtin_amdgcn_s_setprio(1);
#pragma unroll
    for (int m = 0; m < 4; ++m)
#pragma unroll
      for (int n = 0; n < 4; ++n)
        acc[m][n] = __builtin_amdgcn_mfma_f32_16x16x32_f16(af[m], bf[n], acc[m][n], 0, 0, 0);
    __builtin_amdgcn_s_setprio(0);
    cur ^= 1;
  }
#undef LDREGS
#undef WRITE

  const int rg = lane >> 4, cl = lane & 15;
  float* P = part + ((size_t)(grp * BSZ + b) * SEQ + i0) * DIM + d0;
#pragma unroll
  for (int m = 0; m < 4; ++m)
#pragma unroll
    for (int n = 0; n < 4; ++n)
#pragma unroll
      for (int r = 0; r < 4; ++r)
        P[(size_t)(wr * 64 + m * 16 + rg * 4 + r) * DIM + wc * 64 + n * 16 + cl] =
            acc[m][n][r];
}

// K8: hid = f16(sum_g part[g]), 8 groups. grid 1536, block 256
__global__ void k_reduce(const float* __restrict__ part, u16* __restrict__ hid) {
  const size_t i = ((size_t)blockIdx.x * 256 + threadIdx.x) * 4;
  const size_t NHID = (size_t)BSZ * SEQ * DIM;
  float4 s = {0.f, 0.f, 0.f, 0.f};
#pragma unroll
  for (int g = 0; g < 8; ++g) {
    const float4 p = *(const float4*)(part + (size_t)g * NHID + i);
    s.x += p.x; s.y += p.y; s.z += p.z; s.w += p.w;
  }
  *(uint2*)(hid + i) = make_uint2(pk2h(s.x, s.y), pk2h(s.z, s.w));
}

// ---------------------------------------------------------------------------
// K9: logits = hid @ Wb^T — r9 ring re-divided over 512 thr / 8 waves
// (4M x 2N, 64x64 out/wave) for 16 waves/CU (4/SIMD) at 2 blocks/CU.
// Same 3-slice LDS ring (72KB: A 16KB + B 8KB per slice), distance-2
// prefetch, counted vmcnt — now 3 gloads/slice/thread so waits are
// vmcnt(3) mid-loop (slice k+1 stays in flight), tail 3/0. Slot-overwrite
// proof identical to r9 (lgkm-drained reads precede the barrier any STG
// follows). Granule swizzle (lane&3)^((lane>>3)&3) on staged src +
// (kg^((rl>>1)&3)) on frag read — same involution pair (0 conflicts).
// Grid 3144 = 8 i-tiles x 393 v-tiles, XCD-swizzled. Plain stores.
__global__ __launch_bounds__(512, 4) void k_logits(const u16* __restrict__ hid,
                                                   const u16* __restrict__ Wb,
                                                   float* __restrict__ out) {
  __shared__ __align__(16) u16 lds[3 * 12288];  // per slice: A 8192 + B 4096 u16
  const int bid = blockIdx.x;
  const int swz = (bid & 7) * 393 + (bid >> 3);
  const int it = swz & 7, vt = swz >> 3;
  const int i0 = it * 256, v0 = vt * 128;
  const int t = threadIdx.x;
  const int lane = t & 63, w = t >> 6;           // 8 waves
  const int wm = w >> 1, wn = w & 1;             // 4M x 2N, wave = 64x64
  const int rl = lane & 15, kg = lane >> 4;
  const int gsw = (kg ^ ((rl >> 1) & 3)) * 8;    // frag read granule (u16)
  // staging: granule gr = j*512 + w*64 + lane; row = gr>>2, oct swizzled
  const int srow = w * 16 + (lane >> 2);         // base row (j adds 128)
  const int sgr = ((lane & 3) ^ ((lane >> 3) & 3)) * 8;  // pre-swizzled src
  const u16* Abase = hid + ((size_t)i0 + srow) * DIM + sgr;
  const u16* Bbase = Wb + ((size_t)v0 + srow) * DIM + sgr;
  u16* dls = lds + w * 512 + lane * 8;           // + slice*12288 (+j*4096)

#define STG(ss, koff)                                                 \
  {                                                                   \
    const u16* a_ = Abase + (koff);                                   \
    u16* d_ = dls + (ss) * 12288;                                     \
    gload16(a_, d_);                                                  \
    gload16(a_ + (size_t)128 * DIM, d_ + 4096);                       \
    gload16(Bbase + (koff), d_ + 8192);                               \
  }

#define CMP(ss)                                                       \
  {                                                                   \
    half8 af[4], bf[4];                                               \
    _Pragma("unroll") for (int n = 0; n < 4; ++n)                     \
        bf[n] = *(const half8*)(lds + (ss) * 12288 + 8192 +           \
                                (wn * 64 + n * 16 + rl) * 32 + gsw);  \
    _Pragma("unroll") for (int m = 0; m < 4; ++m)                     \
        af[m] = *(const half8*)(lds + (ss) * 12288 +                  \
                                (wm * 64 + m * 16 + rl) * 32 + gsw);  \
    __builtin_amdgcn_s_setprio(1);                                    \
    _Pragma("unroll") for (int m = 0; m < 4; ++m)                     \
        _Pragma("unroll") for (int n = 0; n < 4; ++n)                 \
            acc[m][n] = __builtin_amdgcn_mfma_f32_16x16x32_f16(       \
                af[m], bf[n], acc[m][n], 0, 0, 0);                    \
    __builtin_amdgcn_s_setprio(0);                                    \
  }

#define BARS                                                          \
  __builtin_amdgcn_s_barrier();                                       \
  __builtin_amdgcn_sched_barrier(0);

#define STEPF(ss, st, koff)                                           \
  asm volatile("s_waitcnt vmcnt(3)" ::: "memory");                    \
  BARS;                                                               \
  STG(st, koff);                                                      \
  CMP(ss)

  f32x4 acc[4][4] = {};
  STG(0, 0);
  STG(1, 32);
#pragma unroll 1
  for (int u = 0; u < 7; ++u) {
    const int kb = u * 96;
    STEPF(0, 2, kb + 64);    // slice 3u,   stage 3u+2
    STEPF(1, 0, kb + 96);    // slice 3u+1, stage 3u+3
    STEPF(2, 1, kb + 128);   // slice 3u+2, stage 3u+4
  }
  STEPF(0, 2, 736);          // slice 21, stage 23
  asm volatile("s_waitcnt vmcnt(3)" ::: "memory");  // slice 22 landed
  BARS;
  CMP(1);
  asm volatile("s_waitcnt vmcnt(0)" ::: "memory");  // slice 23 landed
  BARS;
  CMP(2);
#undef STG
#undef CMP
#undef BARS
#undef STEPF

  // epilogue: C col = lane&15 (v), row = (lane>>4)*4 + r (i)
#pragma unroll
  for (int m = 0; m < 4; ++m)
#pragma unroll
    for (int n = 0; n < 4; ++n) {
      const int vv = v0 + wn * 64 + n * 16 + rl;
      if (vv < VOC) {
        const int ib = i0 + wm * 64 + m * 16 + kg * 4;
#pragma unroll
        for (int r = 0; r < 4; ++r)
          out[(size_t)(ib + r) * VOC + vv] = acc[m][n][r];
      }
    }
}

// ---------------------------------------------------------------------------
extern "C" void kernel_launch(void* const* d_in, const int* in_sizes, int n_in,
                              void* d_out, int out_size, void* d_ws, size_t ws_size,
                              hipStream_t stream) {
  const int* ids = (const int*)d_in[0];
  const float* content = (const float*)d_in[1];
  const float* ctx = (const float*)d_in[2];
  const float* W = (const float*)d_in[3];
  const float* cw = (const float*)d_in[4];
  float* out = (float*)d_out;
  char* ws = (char*)d_ws;

  // workspace layout (bytes, all 256-aligned)
  u16* cbf  = (u16*)(ws);                  // 50,331,648  [32][S][D] f16
  u16* cT   = (u16*)(ws + 50331648);       // 50,331,648  [32][D][S] f16
  u16* Wb   = (u16*)(ws + 100663296);      // 77,266,944  [VOCP][D] f16 row-major
  u16* Wg   = (u16*)(ws + 177930240);      //  3,145,728  [B][S][D] f16
  float* sims = (float*)(ws + 248184832);  //    131,072  [32][S] f32
  float* wtsT = (float*)(ws + 248315904);  //    131,072  [32][S] f32
  // aliases (safe by dataflow: source buffer dead before alias first written)
  float* part = (float*)cbf;               // 50,331,648  [8][B][S][D] f32
  u16* hid = Wg;                           //  3,145,728  [B*S][D] f16

  k_prep_content<<<dim3(DIM / 64, SEQ / 64, BSZ * NV), 256, 0, stream>>>(
      content, cbf, cT);
  k_prep_w<<<2048, 256, 0, stream>>>(W, Wb);
  k_gather<<<dim3(SEQ, BSZ), 192, 0, stream>>>(ids, Wb, Wg);
  k_zero<<<128, 256, 0, stream>>>(sims, BSZ * NV * SEQ);
  k_sims<<<dim3(8, 4, BSZ * NV), 256, 0, stream>>>(cbf, Wg, sims);
  k_weights<<<dim3(4, BSZ * NV), 256, 0, stream>>>(sims, ids, cw, wtsT);
  k_hidden<<<768, 256, 0, stream>>>(ctx, wtsT, cT, part);
  k_reduce<<<1536, 256, 0, stream>>>(part, hid);
  k_logits<<<8 * 393, 512, 0, stream>>>(hid, Wb, out);
}

// Round 15
// 547.662 us; speedup vs baseline: 1.0311x; 1.0311x over previous
//
#include <hip/hip_runtime.h>
#include <cstdint>
#include <cstddef>

#define BSZ 2
#define NV 16
#define SEQ 1024
#define DIM 768
#define VOC 50257
#define VOCP 50304   // padded to multiple of 128

typedef unsigned int u32;
typedef unsigned short u16;
typedef _Float16 half8 __attribute__((ext_vector_type(8)));
typedef float f32x4 __attribute__((ext_vector_type(4)));

__device__ __forceinline__ u16 f2h(float f) {
  return __builtin_bit_cast(unsigned short, (_Float16)f);
}
__device__ __forceinline__ u32 pk2h(float a, float b) {
  return (u32)f2h(a) | ((u32)f2h(b) << 16);
}

// async global->LDS, 16B per lane; LDS dest = wave-uniform base + lane*16
__device__ __forceinline__ void gload16(const u16* g, u16* l) {
  __builtin_amdgcn_global_load_lds(
      (const __attribute__((address_space(1))) void*)g,
      (__attribute__((address_space(3))) void*)l, 16, 0, 0);
}

// ---------------------------------------------------------------------------
// K1: content f32 -> f16 (normal + transposed). 64x64 tiles, float4 loads.
// grid (12, 16, 32), block 256
__global__ void k_prep_content(const float* __restrict__ content,
                               u16* __restrict__ cbf, u16* __restrict__ cT) {
  __shared__ u16 tile[64][70];
  const int bk = blockIdx.z;
  const int d0 = blockIdx.x * 64, j0 = blockIdx.y * 64;
  const float* src = content + (size_t)bk * SEQ * DIM;
  u16* dst = cbf + (size_t)bk * SEQ * DIM;
  u16* dstT = cT + (size_t)bk * DIM * SEQ;
  const int c4 = (threadIdx.x & 15) * 4;  // d-local (x4)
  const int r0 = threadIdx.x >> 4;        // 0..15
#pragma unroll
  for (int it = 0; it < 4; ++it) {
    const int r = it * 16 + r0;           // j-local
    const float4 f = *(const float4*)(src + (size_t)(j0 + r) * DIM + d0 + c4);
    const u32 lo = pk2h(f.x, f.y), hi = pk2h(f.z, f.w);
    *(uint2*)(dst + (size_t)(j0 + r) * DIM + d0 + c4) = make_uint2(lo, hi);
    *(u32*)&tile[r][c4] = lo;
    *(u32*)&tile[r][c4 + 2] = hi;
  }
  __syncthreads();
#pragma unroll
  for (int it = 0; it < 4; ++it) {
    const int dd = it * 16 + r0;          // d-local
    const int j4 = c4;                    // j-local (x4)
    const u32 lo = (u32)tile[j4][dd] | ((u32)tile[j4 + 1][dd] << 16);
    const u32 hi = (u32)tile[j4 + 2][dd] | ((u32)tile[j4 + 3][dd] << 16);
    *(uint2*)(dstT + (size_t)(d0 + dd) * SEQ + j0 + j4) = make_uint2(lo, hi);
  }
}

// K2: lm_head_weight f32 -> f16, flat grid-stride (row-major Wb). grid 2048.
__global__ void k_prep_w(const float* __restrict__ W, u16* __restrict__ Wb) {
  const size_t nW = (size_t)VOC * DIM / 4;    // uint2 units covering W
  const size_t total = (size_t)VOCP * DIM / 4;
  for (size_t u = (size_t)blockIdx.x * 256 + threadIdx.x; u < total;
       u += (size_t)gridDim.x * 256) {
    u32 lo = 0u, hi = 0u;
    if (u < nW) {
      const float4 f = *(const float4*)(W + u * 4);
      lo = pk2h(f.x, f.y); hi = pk2h(f.z, f.w);
    }
    *(uint2*)(Wb + u * 4) = make_uint2(lo, hi);
  }
}

// K3: gather Wg[b][j][:] = Wb[ids[b][j]][:]  grid (SEQ, BSZ), block 192
__global__ void k_gather(const int* __restrict__ ids, const u16* __restrict__ Wb,
                         u16* __restrict__ Wg) {
  const int b = blockIdx.y, j = blockIdx.x;
  const int row = ids[b * SEQ + j];
  const int c = threadIdx.x * 4;
  *(uint2*)(Wg + ((size_t)b * SEQ + j) * DIM + c) =
      *(const uint2*)(Wb + (size_t)row * DIM + c);
}

__global__ void k_zero(float* __restrict__ p, int n) {
  const int i = blockIdx.x * 256 + threadIdx.x;
  if (i < n) p[i] = 0.f;
}

// ---------------------------------------------------------------------------
// Dual-A ring core (round-6, verified) — used by k_sims.
template <int LDA, int LDB>
__device__ __forceinline__ void gemm_ring2(const u16* __restrict__ A0,
                                           const u16* __restrict__ A1,
                                           const u16* __restrict__ B, int ksteps,
                                           u16* As0, u16* As1, u16* Bs,
                                           f32x4 (&acc0)[4][4],
                                           f32x4 (&acc1)[4][4], int t) {
  const int lane = t & 63, w = t >> 6, wr = w >> 1, wc = w & 1;
  const int rl = lane & 15;
  const int gsw = (((lane >> 4) ^ ((rl >> 1) & 3)) * 8);
  const int srow = 16 * w + (lane >> 2);
  const int sg = (((lane & 3) ^ ((lane >> 3) & 3)) * 8);
  const size_t gaBase = (size_t)srow * LDA + sg;
  const size_t gbBase = (size_t)srow * LDB + sg;
  const int wof = w * 512;

#define STG3_(ss, kt)                                                   \
  {                                                                     \
    const u16* ga0_ = A0 + gaBase + (size_t)(kt) * 32;                  \
    const u16* ga1_ = A1 + gaBase + (size_t)(kt) * 32;                  \
    const u16* gb_ = B + gbBase + (size_t)(kt) * 32;                    \
    gload16(ga0_, As0 + (ss) * 4096 + wof);                             \
    gload16(ga0_ + (size_t)64 * LDA, As0 + (ss) * 4096 + wof + 2048);   \
    gload16(ga1_, As1 + (ss) * 4096 + wof);                            \
    gload16(ga1_ + (size_t)64 * LDA, As1 + (ss) * 4096 + wof + 2048);   \
    gload16(gb_, Bs + (ss) * 4096 + wof);                              \
    gload16(gb_ + (size_t)64 * LDB, Bs + (ss) * 4096 + wof + 2048);     \
  }

#define FRAGS3_(ss)                                                     \
  half8 af0[4], af1[4], bf[4];                                          \
  _Pragma("unroll") for (int n = 0; n < 4; ++n)                         \
      bf[n] = *(const half8*)(Bs + (ss) * 4096 +                        \
                              (wc * 64 + n * 16 + rl) * 32 + gsw);      \
  _Pragma("unroll") for (int m = 0; m < 4; ++m)                         \
      af0[m] = *(const half8*)(As0 + (ss) * 4096 +                      \
                               (wr * 64 + m * 16 + rl) * 32 + gsw);     \
  _Pragma("unroll") for (int m = 0; m < 4; ++m)                         \
      af1[m] = *(const half8*)(As1 + (ss) * 4096 +                      \
                               (wr * 64 + m * 16 + rl) * 32 + gsw);

#define MFMA32_                                                         \
  __builtin_amdgcn_s_setprio(1);                                        \
  _Pragma("unroll") for (int m = 0; m < 4; ++m)                         \
      _Pragma("unroll") for (int n = 0; n < 4; ++n)                     \
          acc0[m][n] = __builtin_amdgcn_mfma_f32_16x16x32_f16(          \
              af0[m], bf[n], acc0[m][n], 0, 0, 0);                      \
  _Pragma("unroll") for (int m = 0; m < 4; ++m)                         \
      _Pragma("unroll") for (int n = 0; n < 4; ++n)                     \
          acc1[m][n] = __builtin_amdgcn_mfma_f32_16x16x32_f16(          \
              af1[m], bf[n], acc1[m][n], 0, 0, 0);                      \
  __builtin_amdgcn_s_setprio(0);

#define STEPF_(ss, kt)                                                  \
  asm volatile("s_waitcnt vmcnt(6)" ::: "memory");                      \
  __builtin_amdgcn_s_barrier();                                         \
  __builtin_amdgcn_sched_barrier(0);                                    \
  STG3_(((ss) + 2) % 3, (kt) + 2);                                      \
  { FRAGS3_(ss) MFMA32_ }

#define STEPL6_(ss)                                                     \
  asm volatile("s_waitcnt vmcnt(6)" ::: "memory");                      \
  __builtin_amdgcn_s_barrier();                                         \
  __builtin_amdgcn_sched_barrier(0);                                    \
  { FRAGS3_(ss) MFMA32_ }

#define STEPL0_(ss)                                                     \
  asm volatile("s_waitcnt vmcnt(0)" ::: "memory");                      \
  __builtin_amdgcn_s_barrier();                                         \
  __builtin_amdgcn_sched_barrier(0);                                    \
  { FRAGS3_(ss) MFMA32_ }

  STG3_(0, 0);
  STG3_(1, 1);
  const int nTrip = ksteps / 3;
  for (int u = 0; u < nTrip - 1; ++u) {
    const int kt = 3 * u;
    STEPF_(0, kt);
    STEPF_(1, kt + 1);
    STEPF_(2, kt + 2);
  }
  STEPF_(0, ksteps - 3);
  STEPL6_(1);
  STEPL0_(2);
#undef STG3_
#undef FRAGS3_
#undef MFMA32_
#undef STEPF_
#undef STEPL6_
#undef STEPL0_
}

// K4: sims[bk][i] += sum_j relu(content[bk] @ Wg[b]^T). grid (8,4,32)
__global__ __launch_bounds__(256, 2) void k_sims(const u16* __restrict__ cbf,
                                                 const u16* __restrict__ Wg,
                                                 float* __restrict__ sims) {
  __shared__ __align__(16) u16 As0[3 * 4096];
  __shared__ __align__(16) u16 As1[3 * 4096];
  __shared__ __align__(16) u16 Bs[3 * 4096];
  const int bk = blockIdx.z, b = bk >> 4;
  const int t = threadIdx.x;
  const int i0 = blockIdx.y * 256;
  const u16* A0 = cbf + (size_t)bk * SEQ * DIM + (size_t)i0 * DIM;
  const u16* A1 = A0 + (size_t)128 * DIM;
  const u16* B = Wg + (size_t)b * SEQ * DIM + (size_t)(blockIdx.x * 128) * DIM;
  f32x4 acc0[4][4] = {}, acc1[4][4] = {};
  gemm_ring2<DIM, DIM>(A0, A1, B, DIM / 32, As0, As1, Bs, acc0, acc1, t);
  const int lane = t & 63, w = t >> 6, wr = w >> 1;
  const int rg = lane >> 4, cl = lane & 15;
#pragma unroll
  for (int m = 0; m < 4; ++m) {
#pragma unroll
    for (int r = 0; r < 4; ++r) {
      float s0 = 0.f, s1 = 0.f;
#pragma unroll
      for (int n = 0; n < 4; ++n) {
        s0 += fmaxf(acc0[m][n][r], 0.f);
        s1 += fmaxf(acc1[m][n][r], 0.f);
      }
      s0 += __shfl_xor(s0, 1); s1 += __shfl_xor(s1, 1);
      s0 += __shfl_xor(s0, 2); s1 += __shfl_xor(s1, 2);
      s0 += __shfl_xor(s0, 4); s1 += __shfl_xor(s1, 4);
      s0 += __shfl_xor(s0, 8); s1 += __shfl_xor(s1, 8);
      if (cl == 0) {
        const int i = i0 + wr * 64 + m * 16 + rg * 4 + r;
        atomicAdd(&sims[(size_t)bk * SEQ + i], s0);
        atomicAdd(&sims[(size_t)bk * SEQ + i + 128], s1);
      }
    }
  }
}

// K5: wtsT[bk][j] = cw*score + (1-score). grid (4,32), block 256
__global__ void k_weights(const float* __restrict__ sims, const int* __restrict__ ids,
                          const float* __restrict__ cw, float* __restrict__ wtsT) {
  const int j = blockIdx.x * 256 + threadIdx.x;
  const int bk = blockIdx.y;
  const int b = bk >> 4, k = bk & 15;
  const float sm = sims[(size_t)bk * SEQ + j];
  float score = 1.f / (1.f + __expf(0.1f * sm - 6.f));  // sigmoid(-0.1*s + 6)
  score *= 1.f + (float)j * 0.01f;
  const int id = ids[b * SEQ + j];
  const float c = cw[(size_t)id * NV + k];
  wtsT[(size_t)bk * SEQ + j] = c * score + (1.f - score);
}

// ---------------------------------------------------------------------------
// K7 (FUSED ctx-scale + hidden partials) — round-13 verified.
__global__ __launch_bounds__(256, 3) void k_hidden(const float* __restrict__ ctx,
                                                   const float* __restrict__ wtsT,
                                                   const u16* __restrict__ cT,
                                                   float* __restrict__ part) {
  __shared__ __align__(16) u16 As[2 * 4096];
  __shared__ __align__(16) u16 Bs[2 * 4096];
  const int L = blockIdx.x;            // 0..767
  const int g8 = L & 7, q = L >> 3;    // q 0..95
  const int p = g8 * 16 + q / 6;       // (y,z) pair 0..127
  const int dt = q % 6;
  const int y = p & 7, z = p >> 3;
  const int b = z >> 3, grp = z & 7;
  const int i0 = y * 128, d0 = dt * 128;
  const int t = threadIdx.x;
  const int lane = t & 63, w = t >> 6, wr = w >> 1, wc = w & 1;
  const int rl = lane & 15;
  const int gsw = (((lane >> 4) ^ ((rl >> 1) & 3)) * 8);  // frag read granule
  const int srow = 16 * w + (lane >> 2);                  // staging row 0..63
  const int sg = (((lane & 3) ^ ((lane >> 3) & 3)) * 8);  // staged src granule

  f32x4 acc[4][4] = {};
  float4 ra0, ra1, ra2, ra3, rw0, rw1;
  uint4 rb0, rb1;

#define LDREGS(u_)                                                      \
  {                                                                     \
    const int s_ = (u_) >> 5, kt_ = (u_) & 31;                          \
    const size_t bkq_ = (size_t)b * NV + grp * 2 + s_;                  \
    const int jsw_ = kt_ * 32 + sg;                                     \
    const float* ap_ = ctx + (bkq_ * SEQ + i0 + srow) * SEQ + jsw_;     \
    ra0 = *(const float4*)(ap_);                                        \
    ra1 = *(const float4*)(ap_ + 4);                                    \
    ra2 = *(const float4*)(ap_ + (size_t)64 * SEQ);                     \
    ra3 = *(const float4*)(ap_ + (size_t)64 * SEQ + 4);                 \
    const float* wp_ = wtsT + bkq_ * SEQ + jsw_;                        \
    rw0 = *(const float4*)(wp_);                                        \
    rw1 = *(const float4*)(wp_ + 4);                                    \
    const u16* bp_ = cT + (bkq_ * DIM + d0 + srow) * SEQ + jsw_;        \
    rb0 = *(const uint4*)(bp_);                                         \
    rb1 = *(const uint4*)(bp_ + (size_t)64 * SEQ);                      \
  }

#define WRITE(cc)                                                       \
  {                                                                     \
    u16* da_ = As + (cc) * 4096 + w * 512 + lane * 8;                   \
    *(uint4*)(da_) =                                                    \
        make_uint4(pk2h(ra0.x * rw0.x, ra0.y * rw0.y),                  \
                   pk2h(ra0.z * rw0.z, ra0.w * rw0.w),                  \
                   pk2h(ra1.x * rw1.x, ra1.y * rw1.y),                  \
                   pk2h(ra1.z * rw1.z, ra1.w * rw1.w));                 \
    *(uint4*)(da_ + 2048) =                                             \
        make_uint4(pk2h(ra2.x * rw0.x, ra2.y * rw0.y),                  \
                   pk2h(ra2.z * rw0.z, ra2.w * rw0.w),                  \
                   pk2h(ra3.x * rw1.x, ra3.y * rw1.y),                  \
                   pk2h(ra3.z * rw1.z, ra3.w * rw1.w));                 \
    u16* db_ = Bs + (cc) * 4096 + w * 512 + lane * 8;                   \
    *(uint4*)(db_) = rb0;                                               \
    *(uint4*)(db_ + 2048) = rb1;                                        \
  }

  LDREGS(0);
  int cur = 0;
#pragma unroll 1
  for (int u = 0; u < 64; ++u) {
    __syncthreads();              // buffer cur free (its frags consumed)
    WRITE(cur);
    if (u < 63) LDREGS(u + 1);    // issue next-slice loads under compute
    __syncthreads();              // writes visible to all waves
    half8 af[4], bf[4];
#pragma unroll
    for (int m = 0; m < 4; ++m)
      af[m] = *(const half8*)(As + cur * 4096 + (wr * 64 + m * 16 + rl) * 32 + gsw);
#pragma unroll
    for (int n = 0; n < 4; ++n)
      bf[n] = *(const half8*)(Bs + cur * 4096 + (wc * 64 + n * 16 + rl) * 32 + gsw);
    __builtin_amdgcn_s_setprio(1);
#pragma unroll
    for (int m = 0; m < 4; ++m)
#pragma unroll
      for (int n = 0; n < 4; ++n)
        acc[m][n] = __builtin_amdgcn_mfma_f32_16x16x32_f16(af[m], bf[n], acc[m][n], 0, 0, 0);
    __builtin_amdgcn_s_setprio(0);
    cur ^= 1;
  }
#undef LDREGS
#undef WRITE

  const int rg = lane >> 4, cl = lane & 15;
  float* P = part + ((size_t)(grp * BSZ + b) * SEQ + i0) * DIM + d0;
#pragma unroll
  for (int m = 0; m < 4; ++m)
#pragma unroll
    for (int n = 0; n < 4; ++n)
#pragma unroll
      for (int r = 0; r < 4; ++r)
        P[(size_t)(wr * 64 + m * 16 + rg * 4 + r) * DIM + wc * 64 + n * 16 + cl] =
            acc[m][n][r];
}

// K8: hid = f16(sum_g part[g]), 8 groups. grid 1536, block 256
__global__ void k_reduce(const float* __restrict__ part, u16* __restrict__ hid) {
  const size_t i = ((size_t)blockIdx.x * 256 + threadIdx.x) * 4;
  const size_t NHID = (size_t)BSZ * SEQ * DIM;
  float4 s = {0.f, 0.f, 0.f, 0.f};
#pragma unroll
  for (int g = 0; g < 8; ++g) {
    const float4 p = *(const float4*)(part + (size_t)g * NHID + i);
    s.x += p.x; s.y += p.y; s.z += p.z; s.w += p.w;
  }
  *(uint2*)(hid + i) = make_uint2(pk2h(s.x, s.y), pk2h(s.z, s.w));
}

// ---------------------------------------------------------------------------
// K9: logits = hid @ Wb^T — round-9/13 verified 241us version. 256(i) x
// 128(v) tile, 256 thr (4 waves, 2M x 2N, 128x64 out/wave — best LDS-read:
// MFMA ratio reachable in-budget). 3-slice LDS ring (72KB) -> 2 blocks/CU,
// distance-2 prefetch, counted vmcnt(6). Granule swizzle g ^= (row>>1)&3 on
// BOTH staged src and frag read (0 conflicts). Grid 3144 = 8 i-tiles x 393
// v-tiles, XCD-swizzled. Plain stores.
__global__ __launch_bounds__(256, 2) void k_logits(const u16* __restrict__ hid,
                                                   const u16* __restrict__ Wb,
                                                   float* __restrict__ out) {
  __shared__ __align__(16) u16 lds[3 * 12288];  // per slice: A 8192 + B 4096 u16
  const int bid = blockIdx.x;
  const int swz = (bid & 7) * 393 + (bid >> 3);
  const int it = swz & 7, vt = swz >> 3;
  const int i0 = it * 256, v0 = vt * 128;
  const int t = threadIdx.x;
  const int lane = t & 63, w = t >> 6;
  const int wm = w >> 1, wn = w & 1;
  const int rl = lane & 15, kg = lane >> 4;
  const int gsw = (kg ^ ((rl >> 1) & 3)) * 8;          // frag read granule
  const int srow = t >> 2;                             // staging row 0..63
  const int sgr = ((t & 3) ^ ((srow >> 1) & 3)) * 8;   // pre-swizzled src
  const u16* Abase = hid + ((size_t)i0 + srow) * DIM + sgr;
  const u16* Bbase = Wb + ((size_t)v0 + srow) * DIM + sgr;
  u16* dls = lds + t * 8;

#define STG(ss, koff)                                                 \
  {                                                                   \
    const u16* a_ = Abase + (koff);                                   \
    u16* d_ = dls + (ss) * 12288;                                     \
    gload16(a_, d_);                                                  \
    gload16(a_ + (size_t)64 * DIM, d_ + 2048);                        \
    gload16(a_ + (size_t)128 * DIM, d_ + 4096);                       \
    gload16(a_ + (size_t)192 * DIM, d_ + 6144);                       \
    const u16* b_ = Bbase + (koff);                                   \
    gload16(b_, d_ + 8192);                                           \
    gload16(b_ + (size_t)64 * DIM, d_ + 10240);                       \
  }

#define CMP(ss)                                                       \
  {                                                                   \
    half8 af[8], bf[4];                                               \
    _Pragma("unroll") for (int n = 0; n < 4; ++n)                     \
        bf[n] = *(const half8*)(lds + (ss) * 12288 + 8192 +           \
                                (wn * 64 + n * 16 + rl) * 32 + gsw);  \
    _Pragma("unroll") for (int m = 0; m < 8; ++m)                     \
        af[m] = *(const half8*)(lds + (ss) * 12288 +                  \
                                (wm * 128 + m * 16 + rl) * 32 + gsw); \
    __builtin_amdgcn_s_setprio(1);                                    \
    _Pragma("unroll") for (int m = 0; m < 8; ++m)                     \
        _Pragma("unroll") for (int n = 0; n < 4; ++n)                 \
            acc[m][n] = __builtin_amdgcn_mfma_f32_16x16x32_f16(       \
                af[m], bf[n], acc[m][n], 0, 0, 0);                    \
    __builtin_amdgcn_s_setprio(0);                                    \
  }

#define BARS                                                          \
  __builtin_amdgcn_s_barrier();                                       \
  __builtin_amdgcn_sched_barrier(0);

#define STEPF(ss, st, koff)                                           \
  asm volatile("s_waitcnt vmcnt(6)" ::: "memory");                    \
  BARS;                                                               \
  STG(st, koff);                                                      \
  CMP(ss)

  f32x4 acc[8][4] = {};
  STG(0, 0);
  STG(1, 32);
#pragma unroll 1
  for (int u = 0; u < 7; ++u) {
    const int kb = u * 96;
    STEPF(0, 2, kb + 64);    // slice 3u,   stage 3u+2
    STEPF(1, 0, kb + 96);    // slice 3u+1, stage 3u+3
    STEPF(2, 1, kb + 128);   // slice 3u+2, stage 3u+4
  }
  STEPF(0, 2, 736);          // slice 21, stage 23
  asm volatile("s_waitcnt vmcnt(6)" ::: "memory");  // slice 22 landed
  BARS;
  CMP(1);
  asm volatile("s_waitcnt vmcnt(0)" ::: "memory");  // slice 23 landed
  BARS;
  CMP(2);
#undef STG
#undef CMP
#undef BARS
#undef STEPF

  // epilogue: C col = lane&15 (v), row = (lane>>4)*4 + r (i)
#pragma unroll
  for (int m = 0; m < 8; ++m)
#pragma unroll
    for (int n = 0; n < 4; ++n) {
      const int vv = v0 + wn * 64 + n * 16 + rl;
      if (vv < VOC) {
        const int ib = i0 + wm * 128 + m * 16 + kg * 4;
#pragma unroll
        for (int r = 0; r < 4; ++r)
          out[(size_t)(ib + r) * VOC + vv] = acc[m][n][r];
      }
    }
}

// ---------------------------------------------------------------------------
extern "C" void kernel_launch(void* const* d_in, const int* in_sizes, int n_in,
                              void* d_out, int out_size, void* d_ws, size_t ws_size,
                              hipStream_t stream) {
  const int* ids = (const int*)d_in[0];
  const float* content = (const float*)d_in[1];
  const float* ctx = (const float*)d_in[2];
  const float* W = (const float*)d_in[3];
  const float* cw = (const float*)d_in[4];
  float* out = (float*)d_out;
  char* ws = (char*)d_ws;

  // workspace layout (bytes, all 256-aligned)
  u16* cbf  = (u16*)(ws);                  // 50,331,648  [32][S][D] f16
  u16* cT   = (u16*)(ws + 50331648);       // 50,331,648  [32][D][S] f16
  u16* Wb   = (u16*)(ws + 100663296);      // 77,266,944  [VOCP][D] f16 row-major
  u16* Wg   = (u16*)(ws + 177930240);      //  3,145,728  [B][S][D] f16
  float* sims = (float*)(ws + 248184832);  //    131,072  [32][S] f32
  float* wtsT = (float*)(ws + 248315904);  //    131,072  [32][S] f32
  // aliases (safe by dataflow: source buffer dead before alias first written)
  float* part = (float*)cbf;               // 50,331,648  [8][B][S][D] f32
  u16* hid = Wg;                           //  3,145,728  [B*S][D] f16

  k_prep_content<<<dim3(DIM / 64, SEQ / 64, BSZ * NV), 256, 0, stream>>>(
      content, cbf, cT);
  k_prep_w<<<2048, 256, 0, stream>>>(W, Wb);
  k_gather<<<dim3(SEQ, BSZ), 192, 0, stream>>>(ids, Wb, Wg);
  k_zero<<<128, 256, 0, stream>>>(sims, BSZ * NV * SEQ);
  k_sims<<<dim3(8, 4, BSZ * NV), 256, 0, stream>>>(cbf, Wg, sims);
  k_weights<<<dim3(4, BSZ * NV), 256, 0, stream>>>(sims, ids, cw, wtsT);
  k_hidden<<<768, 256, 0, stream>>>(ctx, wtsT, cT, part);
  k_reduce<<<1536, 256, 0, stream>>>(part, hid);
  k_logits<<<8 * 393, 256, 0, stream>>>(hid, Wb, out);
}